// Round 1
// baseline (760.391 us; speedup 1.0000x reference)
//
#include <hip/hip_runtime.h>

#define DD 64
#define RR 16
#define EPSF 1e-9f

__device__ __forceinline__ void fma4(float4& a, const float4& w, float s) {
    a.x = fmaf(w.x, s, a.x); a.y = fmaf(w.y, s, a.y);
    a.z = fmaf(w.z, s, a.z); a.w = fmaf(w.w, s, a.w);
}

// Y[b][n][o] = sum_i x[n][i] * W[r_base + b][i][o], b = blockIdx.y
// block = 128 threads; node tile = 128; per-thread: 16 nodes x 4 outputs.
// LDS: W tile 16KB + transposed/XOR-swizzled x tile 32KB = 48KB.
__global__ __launch_bounds__(128) void k_transform(
    const float* __restrict__ x, const float* __restrict__ W,
    float* __restrict__ Y, int N, int r_base)
{
    __shared__ float ws[DD * DD];    // W[r] row-major [i][o]
    __shared__ float xt[DD * 128];   // [i][swizzled col]
    const int r = r_base + blockIdx.y;
    const int n0 = blockIdx.x * 128;
    const int tid = threadIdx.x;

    {   // stage W[r]: 1024 float4 over 128 threads
        const float4* Wv = (const float4*)(W + (size_t)r * DD * DD);
        float4* wv = (float4*)ws;
        #pragma unroll
        for (int c = 0; c < 8; ++c) wv[c * 128 + tid] = Wv[c * 128 + tid];
    }
    {   // stage x tile transposed; XOR swizzle col4 ^= (i>>2)&7 keeps banks clean
        #pragma unroll
        for (int c = 0; c < 16; ++c) {
            int idx = c * 128 + tid;
            int n  = idx >> 4;            // 0..127
            int i4 = (idx & 15) << 2;     // 0..60
            int gn = n0 + n;
            float4 v = make_float4(0.f, 0.f, 0.f, 0.f);
            if (gn < N) v = ((const float4*)(x + (size_t)gn * DD))[idx & 15];
            int n4 = n >> 2, nr = n & 3;
            float vv[4] = {v.x, v.y, v.z, v.w};
            #pragma unroll
            for (int k = 0; k < 4; ++k) {
                int i = i4 + k;
                int swz = (i >> 2) & 7;
                xt[i * 128 + (((n4 ^ swz) << 2) | nr)] = vv[k];
            }
        }
    }
    __syncthreads();

    const int j  = tid & 15;   // outputs 4j..4j+3
    const int nq = tid >> 4;   // nodes 16nq..16nq+15
    float4 acc[16];
    #pragma unroll
    for (int m = 0; m < 16; ++m) acc[m] = make_float4(0.f, 0.f, 0.f, 0.f);

    #pragma unroll 4
    for (int i = 0; i < DD; ++i) {
        const int swz = (i >> 2) & 7;
        const float4 wv = *(const float4*)&ws[i * DD + 4 * j];
        #pragma unroll
        for (int h = 0; h < 4; ++h) {
            const int col4 = (4 * nq + h) ^ swz;
            const float4 xv = *(const float4*)&xt[i * 128 + (col4 << 2)];
            fma4(acc[4 * h + 0], wv, xv.x);
            fma4(acc[4 * h + 1], wv, xv.y);
            fma4(acc[4 * h + 2], wv, xv.z);
            fma4(acc[4 * h + 3], wv, xv.w);
        }
    }

    const size_t ybase = (size_t)blockIdx.y * N * DD;
    #pragma unroll
    for (int m = 0; m < 16; ++m) {
        int node = n0 + 16 * nq + m;
        if (node < N)
            *(float4*)&Y[ybase + (size_t)node * DD + 4 * j] = acc[m];
    }
}

// Self loops: every node n has exactly one (src=dst=n, attrs at E+n).
// Use them to INITIALIZE aggr (covers all rows; no memset, no atomics).
__global__ __launch_bounds__(256) void k_self(
    const int* __restrict__ et, const float* __restrict__ pl,
    const float* __restrict__ Y, float* __restrict__ aggr, int N, int E)
{
    int idx = blockIdx.x * 256 + threadIdx.x;
    int n = idx >> 6, lane = idx & 63;
    if (n >= N) return;
    int rt = et[E + n];
    float inv = 1.0f / fmaxf(pl[E + n], EPSF);
    aggr[(size_t)n * DD + lane] = Y[((size_t)rt * N + n) * DD + lane] * inv;
}

// One wave per edge: gather Y[rt][src] (256B), scale, 64 fp32 atomics to dst.
// rel_filter >= 0 => chunked-fallback mode (Y holds only that relation).
__global__ __launch_bounds__(256) void k_edges(
    const int* __restrict__ ei, const int* __restrict__ et,
    const float* __restrict__ pl, const float* __restrict__ Y,
    float* __restrict__ aggr, int N, int E, int Etot, int rel_filter)
{
    int wave = threadIdx.x >> 6;
    int lane = threadIdx.x & 63;
    int e = blockIdx.x * 4 + wave;
    if (e >= Etot) return;
    int rt = et[e];
    int yrel;
    if (rel_filter >= 0) { if (rt != rel_filter) return; yrel = 0; }
    else yrel = rt;
    int src, dst;
    if (e < E) { src = ei[e]; dst = ei[E + e]; }
    else       { src = dst = e - E; }
    float inv = 1.0f / fmaxf(pl[e], EPSF);
    float v = Y[((size_t)yrel * N + src) * DD + lane] * inv;
    atomicAdd(&aggr[(size_t)dst * DD + lane], v);
}

__global__ __launch_bounds__(256) void k_bias_relu(
    const float* __restrict__ aggr, const float* __restrict__ bias,
    float* __restrict__ out, int N)
{
    int idx = blockIdx.x * 256 + threadIdx.x;   // float4 index
    if (idx >= N * (DD / 4)) return;
    float4 a = ((const float4*)aggr)[idx];
    int o4 = (idx & 15) * 4;
    a.x = fmaxf(a.x + bias[o4 + 0], 0.f);
    a.y = fmaxf(a.y + bias[o4 + 1], 0.f);
    a.z = fmaxf(a.z + bias[o4 + 2], 0.f);
    a.w = fmaxf(a.w + bias[o4 + 3], 0.f);
    ((float4*)out)[idx] = a;
}

__global__ __launch_bounds__(256) void k_zero(float* __restrict__ p, size_t n)
{
    size_t i = (size_t)blockIdx.x * 256 + threadIdx.x;
    size_t stride = (size_t)gridDim.x * 256;
    for (; i < n; i += stride) p[i] = 0.f;
}

extern "C" void kernel_launch(void* const* d_in, const int* in_sizes, int n_in,
                              void* d_out, int out_size, void* d_ws, size_t ws_size,
                              hipStream_t stream)
{
    const float* x  = (const float*)d_in[0];
    const int*   ei = (const int*)d_in[1];
    const int*   et = (const int*)d_in[2];
    const float* pl = (const float*)d_in[3];
    const float* W1 = (const float*)d_in[4];
    const float* b1 = (const float*)d_in[5];
    const float* W2 = (const float*)d_in[6];
    const float* b2 = (const float*)d_in[7];
    float* out = (float*)d_out;

    const int N = in_sizes[0] / DD;
    const int E = in_sizes[1] / 2;
    const size_t ndf = (size_t)N * DD;

    float* wsp = (float*)d_ws;
    const size_t need_full = (size_t)(RR + 1) * ndf * sizeof(float);
    const bool full = ws_size >= need_full;

    float* Y     = wsp;                                  // R*N*D (full) or N*D (chunk)
    float* aggr1 = full ? (wsp + (size_t)RR * ndf) : (wsp + ndf);
    // layer-1 hidden state lives in aggr1 (bias_relu in place);
    // layer-2 accumulator is d_out itself (bias_relu in place).

    const int gx      = (N + 127) / 128;
    const int gEdge   = (E + 3) / 4;
    const int gEdgeT  = (E + N + 3) / 4;
    const int gNode   = (N * DD + 255) / 256;
    const int gQuad   = (N * (DD / 4) + 255) / 256;

    for (int layer = 0; layer < 2; ++layer) {
        const float* xin  = layer ? aggr1 : x;
        const float* W    = layer ? W2 : W1;
        const float* bias = layer ? b2 : b1;
        float* aggr       = layer ? out : aggr1;

        if (full) {
            k_transform<<<dim3(gx, RR), 128, 0, stream>>>(xin, W, Y, N, 0);
            k_self<<<gNode, 256, 0, stream>>>(et, pl, Y, aggr, N, E);
            k_edges<<<gEdge, 256, 0, stream>>>(ei, et, pl, Y, aggr, N, E, E, -1);
        } else {
            k_zero<<<1024, 256, 0, stream>>>(aggr, ndf);
            for (int r = 0; r < RR; ++r) {
                k_transform<<<dim3(gx, 1), 128, 0, stream>>>(xin, W, Y, N, r);
                k_edges<<<gEdgeT, 256, 0, stream>>>(ei, et, pl, Y, aggr, N, E, E + N, r);
            }
        }
        k_bias_relu<<<gQuad, 256, 0, stream>>>(aggr, bias, aggr == out ? out : aggr1, N);
    }
}

// Round 2
// 540.456 us; speedup vs baseline: 1.4069x; 1.4069x over previous
//
#include <hip/hip_runtime.h>

#define DD 64
#define RR 16
#define EPSF 1e-9f

__device__ __forceinline__ void fma4(float4& a, const float4& w, float s) {
    a.x = fmaf(w.x, s, a.x); a.y = fmaf(w.y, s, a.y);
    a.z = fmaf(w.z, s, a.z); a.w = fmaf(w.w, s, a.w);
}

// Y[b][n][o] = sum_i x[n][i] * W[r_base + b][i][o], b = blockIdx.y
__global__ __launch_bounds__(128) void k_transform(
    const float* __restrict__ x, const float* __restrict__ W,
    float* __restrict__ Y, int N, int r_base)
{
    __shared__ float ws[DD * DD];
    __shared__ float xt[DD * 128];
    const int r = r_base + blockIdx.y;
    const int n0 = blockIdx.x * 128;
    const int tid = threadIdx.x;

    {
        const float4* Wv = (const float4*)(W + (size_t)r * DD * DD);
        float4* wv = (float4*)ws;
        #pragma unroll
        for (int c = 0; c < 8; ++c) wv[c * 128 + tid] = Wv[c * 128 + tid];
    }
    {
        #pragma unroll
        for (int c = 0; c < 16; ++c) {
            int idx = c * 128 + tid;
            int n  = idx >> 4;
            int i4 = (idx & 15) << 2;
            int gn = n0 + n;
            float4 v = make_float4(0.f, 0.f, 0.f, 0.f);
            if (gn < N) v = ((const float4*)(x + (size_t)gn * DD))[idx & 15];
            int n4 = n >> 2, nr = n & 3;
            float vv[4] = {v.x, v.y, v.z, v.w};
            #pragma unroll
            for (int k = 0; k < 4; ++k) {
                int i = i4 + k;
                int swz = (i >> 2) & 7;
                xt[i * 128 + (((n4 ^ swz) << 2) | nr)] = vv[k];
            }
        }
    }
    __syncthreads();

    const int j  = tid & 15;
    const int nq = tid >> 4;
    float4 acc[16];
    #pragma unroll
    for (int m = 0; m < 16; ++m) acc[m] = make_float4(0.f, 0.f, 0.f, 0.f);

    #pragma unroll 4
    for (int i = 0; i < DD; ++i) {
        const int swz = (i >> 2) & 7;
        const float4 wv = *(const float4*)&ws[i * DD + 4 * j];
        #pragma unroll
        for (int h = 0; h < 4; ++h) {
            const int col4 = (4 * nq + h) ^ swz;
            const float4 xv = *(const float4*)&xt[i * 128 + (col4 << 2)];
            fma4(acc[4 * h + 0], wv, xv.x);
            fma4(acc[4 * h + 1], wv, xv.y);
            fma4(acc[4 * h + 2], wv, xv.z);
            fma4(acc[4 * h + 3], wv, xv.w);
        }
    }

    const size_t ybase = (size_t)blockIdx.y * N * DD;
    #pragma unroll
    for (int m = 0; m < 16; ++m) {
        int node = n0 + 16 * nq + m;
        if (node < N)
            *(float4*)&Y[ybase + (size_t)node * DD + 4 * j] = acc[m];
    }
}

// ---------------- CSR build (once per call; edge list shared by both layers) ----

__global__ __launch_bounds__(256) void k_zero_int(int* __restrict__ p, int n)
{
    int i = blockIdx.x * 256 + threadIdx.x;
    if (i < n) p[i] = 0;
}

__global__ __launch_bounds__(256) void k_hist(
    const int* __restrict__ ei, int* __restrict__ deg, int E)
{
    int e = blockIdx.x * 256 + threadIdx.x;
    if (e < E) atomicAdd(&deg[ei[E + e]], 1);
}

// Exclusive scan, two-level. Block = 256 threads x 4 elems = 1024.
__global__ __launch_bounds__(256) void k_scanA(
    const int* __restrict__ deg, int* __restrict__ rowptr,
    int* __restrict__ bsum, int N)
{
    __shared__ int sh[256];
    const int b = blockIdx.x, t = threadIdx.x;
    const int base = b * 1024 + t * 4;
    int v[4], s = 0;
    #pragma unroll
    for (int k = 0; k < 4; ++k) {
        int i = base + k;
        v[k] = (i < N) ? deg[i] : 0;
        s += v[k];
    }
    sh[t] = s;
    __syncthreads();
    for (int off = 1; off < 256; off <<= 1) {
        int tmp = (t >= off) ? sh[t - off] : 0;
        __syncthreads();
        sh[t] += tmp;
        __syncthreads();
    }
    if (t == 255) bsum[b] = sh[255];
    int run = sh[t] - s;  // exclusive prefix of this thread's chunk
    #pragma unroll
    for (int k = 0; k < 4; ++k) {
        int i = base + k;
        if (i < N) rowptr[i] = run;
        run += v[k];
    }
}

__global__ __launch_bounds__(256) void k_scanB(int* __restrict__ bsum, int nb)
{
    __shared__ int sh[256];
    int t = threadIdx.x;
    int v = (t < nb) ? bsum[t] : 0;
    sh[t] = v;
    __syncthreads();
    for (int off = 1; off < 256; off <<= 1) {
        int tmp = (t >= off) ? sh[t - off] : 0;
        __syncthreads();
        sh[t] += tmp;
        __syncthreads();
    }
    if (t < nb) bsum[t] = sh[t] - v;  // exclusive
}

__global__ __launch_bounds__(256) void k_scanC(
    int* __restrict__ rowptr, int* __restrict__ cursor,
    const int* __restrict__ bsum, int N, int E)
{
    int i = blockIdx.x * 256 + threadIdx.x;
    if (i < N) {
        int v = rowptr[i] + bsum[i >> 10];
        rowptr[i] = v;
        cursor[i] = v;
    }
    if (i == N) rowptr[N] = E;
}

__global__ __launch_bounds__(256) void k_scatter(
    const int* __restrict__ ei, const int* __restrict__ et,
    const float* __restrict__ pl, int* __restrict__ cursor,
    int* __restrict__ packed, float* __restrict__ einv, int E)
{
    int e = blockIdx.x * 256 + threadIdx.x;
    if (e >= E) return;
    int dst = ei[E + e];
    int src = ei[e];
    int rt  = et[e];
    float iv = 1.0f / fmaxf(pl[e], EPSF);
    int pos = atomicAdd(&cursor[dst], 1);
    packed[pos] = src | (rt << 20);
    einv[pos] = iv;
}

// ---------------- fused aggregate: self-loop init + edge gather + bias + relu ---

__global__ __launch_bounds__(256) void k_aggregate(
    const float* __restrict__ Y, const int* __restrict__ rowptr,
    const int* __restrict__ packed, const float* __restrict__ einv,
    const int* __restrict__ et, const float* __restrict__ pl,
    const float* __restrict__ bias, float* __restrict__ out, int N, int E)
{
    const int n = blockIdx.x * 4 + (threadIdx.x >> 6);
    const int lane = threadIdx.x & 63;
    if (n >= N) return;

    // self loop initializes the accumulator (bijective: one per node)
    int rts = et[E + n];
    float ivs = 1.0f / fmaxf(pl[E + n], EPSF);
    float acc = Y[((size_t)rts * N + n) * DD + lane] * ivs;

    const int beg = rowptr[n], end = rowptr[n + 1];
    for (int p0 = beg; p0 < end; p0 += 64) {
        int cnt = end - p0; if (cnt > 64) cnt = 64;
        int pk = 0; float iv = 0.f;
        if (lane < cnt) { pk = packed[p0 + lane]; iv = einv[p0 + lane]; }
        #pragma unroll 2
        for (int j = 0; j < cnt; ++j) {
            int pkj = __shfl(pk, j);
            float ivj = __shfl(iv, j);
            const float* yp = Y + (((size_t)(pkj >> 20)) * N + (pkj & 0xFFFFF)) * DD;
            acc = fmaf(yp[lane], ivj, acc);
        }
    }
    out[(size_t)n * DD + lane] = fmaxf(acc + bias[lane], 0.f);
}

// ---------------- fallback kernels (small-ws paths) -----------------------------

__global__ __launch_bounds__(256) void k_self(
    const int* __restrict__ et, const float* __restrict__ pl,
    const float* __restrict__ Y, float* __restrict__ aggr, int N, int E)
{
    int idx = blockIdx.x * 256 + threadIdx.x;
    int n = idx >> 6, lane = idx & 63;
    if (n >= N) return;
    int rt = et[E + n];
    float inv = 1.0f / fmaxf(pl[E + n], EPSF);
    aggr[(size_t)n * DD + lane] = Y[((size_t)rt * N + n) * DD + lane] * inv;
}

__global__ __launch_bounds__(256) void k_edges(
    const int* __restrict__ ei, const int* __restrict__ et,
    const float* __restrict__ pl, const float* __restrict__ Y,
    float* __restrict__ aggr, int N, int E, int Etot, int rel_filter)
{
    int wave = threadIdx.x >> 6;
    int lane = threadIdx.x & 63;
    int e = blockIdx.x * 4 + wave;
    if (e >= Etot) return;
    int rt = et[e];
    int yrel;
    if (rel_filter >= 0) { if (rt != rel_filter) return; yrel = 0; }
    else yrel = rt;
    int src, dst;
    if (e < E) { src = ei[e]; dst = ei[E + e]; }
    else       { src = dst = e - E; }
    float inv = 1.0f / fmaxf(pl[e], EPSF);
    float v = Y[((size_t)yrel * N + src) * DD + lane] * inv;
    atomicAdd(&aggr[(size_t)dst * DD + lane], v);
}

__global__ __launch_bounds__(256) void k_bias_relu(
    const float* __restrict__ aggr, const float* __restrict__ bias,
    float* __restrict__ out, int N)
{
    int idx = blockIdx.x * 256 + threadIdx.x;
    if (idx >= N * (DD / 4)) return;
    float4 a = ((const float4*)aggr)[idx];
    int o4 = (idx & 15) * 4;
    a.x = fmaxf(a.x + bias[o4 + 0], 0.f);
    a.y = fmaxf(a.y + bias[o4 + 1], 0.f);
    a.z = fmaxf(a.z + bias[o4 + 2], 0.f);
    a.w = fmaxf(a.w + bias[o4 + 3], 0.f);
    ((float4*)out)[idx] = a;
}

__global__ __launch_bounds__(256) void k_zero(float* __restrict__ p, size_t n)
{
    size_t i = (size_t)blockIdx.x * 256 + threadIdx.x;
    size_t stride = (size_t)gridDim.x * 256;
    for (; i < n; i += stride) p[i] = 0.f;
}

extern "C" void kernel_launch(void* const* d_in, const int* in_sizes, int n_in,
                              void* d_out, int out_size, void* d_ws, size_t ws_size,
                              hipStream_t stream)
{
    const float* x  = (const float*)d_in[0];
    const int*   ei = (const int*)d_in[1];
    const int*   et = (const int*)d_in[2];
    const float* pl = (const float*)d_in[3];
    const float* W1 = (const float*)d_in[4];
    const float* b1 = (const float*)d_in[5];
    const float* W2 = (const float*)d_in[6];
    const float* b2 = (const float*)d_in[7];
    float* out = (float*)d_out;

    const int N = in_sizes[0] / DD;
    const int E = in_sizes[1] / 2;
    const size_t ndf = (size_t)N * DD;

    float* wsp = (float*)d_ws;
    float* Y     = wsp;
    float* aggr1 = wsp + (size_t)RR * ndf;

    // CSR region after Y + aggr1
    int* rowptr  = (int*)(wsp + (size_t)(RR + 1) * ndf);
    int* cursor  = rowptr + (N + 1);
    int* bsum    = cursor + N;
    int* packed  = bsum + 256;
    float* einv  = (float*)(packed + E);

    const size_t need_full = (size_t)(RR + 1) * ndf * sizeof(float);
    const size_t need_csr  = need_full +
        ((size_t)(N + 1) + N + 256 + E + E) * sizeof(int);
    const int nb_scan = (N + 1023) / 1024;
    const bool csr_ok  = (ws_size >= need_csr) && (nb_scan <= 256);
    const bool full_ok = ws_size >= need_full;

    const int gx     = (N + 127) / 128;
    const int gE256  = (E + 255) / 256;
    const int gNode  = (N * DD + 255) / 256;
    const int gQuad  = (N * (DD / 4) + 255) / 256;
    const int gAggr  = (N + 3) / 4;
    const int gEdge  = (E + 3) / 4;
    const int gEdgeT = (E + N + 3) / 4;

    if (csr_ok) {
        // build CSR once; reused by both layers
        k_zero_int<<<(N + 256) / 256, 256, 0, stream>>>(rowptr, N + 1);
        k_hist<<<gE256, 256, 0, stream>>>(ei, rowptr, E);  // rowptr as deg
        k_scanA<<<nb_scan, 256, 0, stream>>>(rowptr, rowptr, bsum, N);
        k_scanB<<<1, 256, 0, stream>>>(bsum, nb_scan);
        k_scanC<<<(N + 256) / 256, 256, 0, stream>>>(rowptr, cursor, bsum, N, E);
        k_scatter<<<gE256, 256, 0, stream>>>(ei, et, pl, cursor, packed, einv, E);

        for (int layer = 0; layer < 2; ++layer) {
            const float* xin  = layer ? aggr1 : x;
            const float* W    = layer ? W2 : W1;
            const float* bias = layer ? b2 : b1;
            float* dest       = layer ? out : aggr1;
            k_transform<<<dim3(gx, RR), 128, 0, stream>>>(xin, W, Y, N, 0);
            k_aggregate<<<gAggr, 256, 0, stream>>>(Y, rowptr, packed, einv,
                                                   et, pl, bias, dest, N, E);
        }
        return;
    }

    // fallback paths (atomic-based)
    for (int layer = 0; layer < 2; ++layer) {
        const float* xin  = layer ? aggr1 : x;
        const float* W    = layer ? W2 : W1;
        const float* bias = layer ? b2 : b1;
        float* aggr       = layer ? out : aggr1;

        if (full_ok) {
            k_transform<<<dim3(gx, RR), 128, 0, stream>>>(xin, W, Y, N, 0);
            k_self<<<gNode, 256, 0, stream>>>(et, pl, Y, aggr, N, E);
            k_edges<<<gEdge, 256, 0, stream>>>(ei, et, pl, Y, aggr, N, E, E, -1);
        } else {
            float* Yc = wsp;
            float* ag = wsp + ndf;
            if (layer == 0) aggr1 = ag;
            aggr = layer ? out : ag;
            k_zero<<<1024, 256, 0, stream>>>(aggr, ndf);
            for (int r = 0; r < RR; ++r) {
                k_transform<<<dim3(gx, 1), 128, 0, stream>>>(xin, W, Yc, N, r);
                k_edges<<<gEdgeT, 256, 0, stream>>>(ei, et, pl, Yc, aggr, N, E, E + N, r);
            }
        }
        k_bias_relu<<<gQuad, 256, 0, stream>>>(aggr, bias, aggr == out ? out : aggr1, N);
    }
}

// Round 3
// 467.012 us; speedup vs baseline: 1.6282x; 1.1573x over previous
//
#include <hip/hip_runtime.h>

#define DD 64
#define RR 16
#define EPSF 1e-9f

typedef unsigned int uint32_tt;
typedef unsigned short ushort_t;

__device__ __forceinline__ void fma4(float4& a, const float4& w, float s) {
    a.x = fmaf(w.x, s, a.x); a.y = fmaf(w.y, s, a.y);
    a.z = fmaf(w.z, s, a.z); a.w = fmaf(w.w, s, a.w);
}

__device__ __forceinline__ unsigned f2bf(float f) {
    unsigned u = __float_as_uint(f);
    return (u + 0x7FFFu + ((u >> 16) & 1u)) >> 16;   // RNE
}
__device__ __forceinline__ uint2 pk4(float4 v) {
    return make_uint2(f2bf(v.x) | (f2bf(v.y) << 16),
                      f2bf(v.z) | (f2bf(v.w) << 16));
}
__device__ __forceinline__ float bf_lo(unsigned u) { return __uint_as_float(u << 16); }
__device__ __forceinline__ float bf_hi(unsigned u) { return __uint_as_float(u & 0xFFFF0000u); }

// Y[r][n][o] (bf16) = sum_i x[n][i] * W[r][i][o].
// Block: 256 thr, node tile 128, loops r_cnt relations (x staged ONCE).
// LDS: xt 32KB (transposed+XOR-swizzled) + ws 16KB = 48KB -> 3 blocks/CU.
__global__ __launch_bounds__(256) void k_transform(
    const float* __restrict__ x, const float* __restrict__ W,
    ushort_t* __restrict__ Y, int N, int r_base, int r_cnt, int yr_off)
{
    __shared__ float xt[DD * 128];
    __shared__ float ws[DD * DD];
    const int n0 = blockIdx.x * 128;
    const int tid = threadIdx.x;

    #pragma unroll
    for (int c = 0; c < 8; ++c) {          // stage x tile: 2048 float4
        int idx = c * 256 + tid;
        int n  = idx >> 4;
        int i4 = (idx & 15) << 2;
        int gn = n0 + n;
        float4 v = make_float4(0.f, 0.f, 0.f, 0.f);
        if (gn < N) v = ((const float4*)(x + (size_t)gn * DD))[idx & 15];
        int n4 = n >> 2, nr = n & 3;
        float vv[4] = {v.x, v.y, v.z, v.w};
        #pragma unroll
        for (int k = 0; k < 4; ++k) {
            int i = i4 + k;
            int swz = (i >> 2) & 7;
            xt[i * 128 + (((n4 ^ swz) << 2) | nr)] = vv[k];
        }
    }

    const int j  = tid & 15;   // outs 4j..4j+3
    const int nq = tid >> 4;   // nodes 8nq..8nq+7

    for (int rr = 0; rr < r_cnt; ++rr) {
        const int r = r_base + blockIdx.y * r_cnt + rr;
        __syncthreads();                    // ws reuse barrier (also covers xt)
        {
            const float4* Wv = (const float4*)(W + (size_t)r * DD * DD);
            float4* wv = (float4*)ws;
            #pragma unroll
            for (int c = 0; c < 4; ++c) wv[c * 256 + tid] = Wv[c * 256 + tid];
        }
        __syncthreads();

        float4 acc[8];
        #pragma unroll
        for (int m = 0; m < 8; ++m) acc[m] = make_float4(0.f, 0.f, 0.f, 0.f);

        #pragma unroll 4
        for (int i = 0; i < DD; ++i) {
            const int swz = (i >> 2) & 7;
            const float4 wv = *(const float4*)&ws[i * DD + 4 * j];
            #pragma unroll
            for (int h = 0; h < 2; ++h) {
                const int col4 = (2 * nq + h) ^ swz;
                const float4 xv = *(const float4*)&xt[i * 128 + (col4 << 2)];
                fma4(acc[4 * h + 0], wv, xv.x);
                fma4(acc[4 * h + 1], wv, xv.y);
                fma4(acc[4 * h + 2], wv, xv.z);
                fma4(acc[4 * h + 3], wv, xv.w);
            }
        }

        const size_t ybase = (size_t)(r - yr_off) * N;
        #pragma unroll
        for (int m = 0; m < 8; ++m) {
            int node = n0 + 8 * nq + 4 * (m >> 2) + (m & 3);
            if (node < N)
                *(uint2*)(Y + (ybase + node) * DD + 4 * j) = pk4(acc[m]);
        }
    }
}

// ---------------- CSR build ----------------------------------------------------

__global__ __launch_bounds__(256) void k_zero_int(int* __restrict__ p, int n)
{
    int i = blockIdx.x * 256 + threadIdx.x;
    if (i < n) p[i] = 0;
}

__global__ __launch_bounds__(256) void k_hist(
    const int* __restrict__ ei, int* __restrict__ deg, int E)
{
    int e = blockIdx.x * 256 + threadIdx.x;
    if (e < E) atomicAdd(&deg[ei[E + e]], 1);
}

__global__ __launch_bounds__(256) void k_scanA(
    const int* __restrict__ deg, int* __restrict__ rowptr,
    int* __restrict__ bsum, int N)
{
    __shared__ int sh[256];
    const int b = blockIdx.x, t = threadIdx.x;
    const int base = b * 1024 + t * 4;
    int v[4], s = 0;
    #pragma unroll
    for (int k = 0; k < 4; ++k) {
        int i = base + k;
        v[k] = (i < N) ? deg[i] : 0;
        s += v[k];
    }
    sh[t] = s;
    __syncthreads();
    for (int off = 1; off < 256; off <<= 1) {
        int tmp = (t >= off) ? sh[t - off] : 0;
        __syncthreads();
        sh[t] += tmp;
        __syncthreads();
    }
    if (t == 255) bsum[b] = sh[255];
    int run = sh[t] - s;
    #pragma unroll
    for (int k = 0; k < 4; ++k) {
        int i = base + k;
        if (i < N) rowptr[i] = run;
        run += v[k];
    }
}

__global__ __launch_bounds__(256) void k_scanB(int* __restrict__ bsum, int nb)
{
    __shared__ int sh[256];
    int t = threadIdx.x;
    int v = (t < nb) ? bsum[t] : 0;
    sh[t] = v;
    __syncthreads();
    for (int off = 1; off < 256; off <<= 1) {
        int tmp = (t >= off) ? sh[t - off] : 0;
        __syncthreads();
        sh[t] += tmp;
        __syncthreads();
    }
    if (t < nb) bsum[t] = sh[t] - v;
}

__global__ __launch_bounds__(256) void k_scanC(
    int* __restrict__ rowptr, int* __restrict__ cursor,
    const int* __restrict__ bsum, int N, int E)
{
    int i = blockIdx.x * 256 + threadIdx.x;
    if (i < N) {
        int v = rowptr[i] + bsum[i >> 10];
        rowptr[i] = v;
        cursor[i] = v;
    }
    if (i == N) rowptr[N] = E;
}

__global__ __launch_bounds__(256) void k_scatter(
    const int* __restrict__ ei, const int* __restrict__ et,
    const float* __restrict__ pl, int* __restrict__ cursor,
    uint2* __restrict__ ep, int E)
{
    int e = blockIdx.x * 256 + threadIdx.x;
    if (e >= E) return;
    int dst = ei[E + e];
    int src = ei[e];
    int rt  = et[e];
    float iv = 1.0f / fmaxf(pl[e], EPSF);
    int pos = atomicAdd(&cursor[dst], 1);
    ep[pos] = make_uint2((unsigned)src | ((unsigned)rt << 20), __float_as_uint(iv));
}

// ---------------- fused aggregate: half-wave per node --------------------------
// 32 lanes x 2 outs = exact 128B bf16 row. Self-loop init + gather + bias + relu.

__global__ __launch_bounds__(256) void k_aggregate(
    const ushort_t* __restrict__ Y, const int* __restrict__ rowptr,
    const uint2* __restrict__ ep,
    const int* __restrict__ et, const float* __restrict__ pl,
    const float* __restrict__ bias, float* __restrict__ out, int N, int E)
{
    const int n = blockIdx.x * 8 + (threadIdx.x >> 5);
    const int lane = threadIdx.x & 31;
    if (n >= N) return;

    int rts = et[E + n];
    float ivs = 1.0f / fmaxf(pl[E + n], EPSF);
    unsigned yv = *(const unsigned*)(Y + ((size_t)rts * N + n) * DD + 2 * lane);
    float accx = bf_lo(yv) * ivs;
    float accy = bf_hi(yv) * ivs;

    const int beg = rowptr[n], end = rowptr[n + 1];
    for (int p0 = beg; p0 < end; p0 += 32) {
        int cnt = end - p0; if (cnt > 32) cnt = 32;
        unsigned pk = 0, ivb = 0;
        if (lane < cnt) { uint2 m = ep[p0 + lane]; pk = m.x; ivb = m.y; }
        for (int jj = 0; jj < cnt; ++jj) {
            unsigned pkj = (unsigned)__shfl((int)pk, jj, 32);
            float ivj = __uint_as_float((unsigned)__shfl((int)ivb, jj, 32));
            const ushort_t* yp = Y + (((size_t)(pkj >> 20)) * N + (pkj & 0xFFFFFu)) * DD;
            unsigned v = *(const unsigned*)(yp + 2 * lane);
            accx = fmaf(bf_lo(v), ivj, accx);
            accy = fmaf(bf_hi(v), ivj, accy);
        }
    }
    float2 bb = *(const float2*)(bias + 2 * lane);
    float2 o;
    o.x = fmaxf(accx + bb.x, 0.f);
    o.y = fmaxf(accy + bb.y, 0.f);
    *(float2*)(out + (size_t)n * DD + 2 * lane) = o;
}

// ---------------- fallback (chunked, atomic) -----------------------------------

__global__ __launch_bounds__(256) void k_edges(
    const int* __restrict__ ei, const int* __restrict__ et,
    const float* __restrict__ pl, const ushort_t* __restrict__ Y,
    float* __restrict__ aggr, int N, int E, int Etot, int rel_filter)
{
    int sub = threadIdx.x >> 5;
    int lane = threadIdx.x & 31;
    int e = blockIdx.x * 8 + sub;
    if (e >= Etot) return;
    int rt = et[e];
    int yrel = rt;
    if (rel_filter >= 0) { if (rt != rel_filter) return; yrel = 0; }
    int src, dst;
    if (e < E) { src = ei[e]; dst = ei[E + e]; }
    else       { src = dst = e - E; }
    float inv = 1.0f / fmaxf(pl[e], EPSF);
    unsigned v = *(const unsigned*)(Y + ((size_t)yrel * N + src) * DD + 2 * lane);
    atomicAdd(&aggr[(size_t)dst * DD + 2 * lane],     bf_lo(v) * inv);
    atomicAdd(&aggr[(size_t)dst * DD + 2 * lane + 1], bf_hi(v) * inv);
}

__global__ __launch_bounds__(256) void k_bias_relu(
    const float* __restrict__ aggr, const float* __restrict__ bias,
    float* __restrict__ out, int N)
{
    int idx = blockIdx.x * 256 + threadIdx.x;
    if (idx >= N * (DD / 4)) return;
    float4 a = ((const float4*)aggr)[idx];
    int o4 = (idx & 15) * 4;
    a.x = fmaxf(a.x + bias[o4 + 0], 0.f);
    a.y = fmaxf(a.y + bias[o4 + 1], 0.f);
    a.z = fmaxf(a.z + bias[o4 + 2], 0.f);
    a.w = fmaxf(a.w + bias[o4 + 3], 0.f);
    ((float4*)out)[idx] = a;
}

__global__ __launch_bounds__(256) void k_zero(float* __restrict__ p, size_t n)
{
    size_t i = (size_t)blockIdx.x * 256 + threadIdx.x;
    size_t stride = (size_t)gridDim.x * 256;
    for (; i < n; i += stride) p[i] = 0.f;
}

extern "C" void kernel_launch(void* const* d_in, const int* in_sizes, int n_in,
                              void* d_out, int out_size, void* d_ws, size_t ws_size,
                              hipStream_t stream)
{
    const float* x  = (const float*)d_in[0];
    const int*   ei = (const int*)d_in[1];
    const int*   et = (const int*)d_in[2];
    const float* pl = (const float*)d_in[3];
    const float* W1 = (const float*)d_in[4];
    const float* b1 = (const float*)d_in[5];
    const float* W2 = (const float*)d_in[6];
    const float* b2 = (const float*)d_in[7];
    float* out = (float*)d_out;

    const int N = in_sizes[0] / DD;
    const int E = in_sizes[1] / 2;
    const size_t ndf = (size_t)N * DD;

    // workspace layout (bf16 Y)
    char* wsb = (char*)d_ws;
    ushort_t* Y  = (ushort_t*)wsb;                       // RR*ndf bf16
    float* aggr1 = (float*)(wsb + (size_t)RR * ndf * 2); // ndf fp32
    int* rowptr  = (int*)((char*)aggr1 + ndf * 4);       // N+1
    int* cursor  = rowptr + (N + 1);                     // N
    int* bsum    = cursor + N;                           // 256 (+1 pad)
    uint2* ep    = (uint2*)(bsum + 256 + 1);             // E

    const size_t need_main = (size_t)RR * ndf * 2 + ndf * 4 +
        ((size_t)(N + 1) + N + 257) * 4 + (size_t)E * 8;
    const int nb_scan = (N + 1023) / 1024;
    const bool main_ok = (ws_size >= need_main) && (nb_scan <= 256);

    const int gx = (N + 127) / 128;

    if (main_ok) {
        k_zero_int<<<(N + 256) / 256, 256, 0, stream>>>(rowptr, N + 1);
        k_hist<<<(E + 255) / 256, 256, 0, stream>>>(ei, rowptr, E);
        k_scanA<<<nb_scan, 256, 0, stream>>>(rowptr, rowptr, bsum, N);
        k_scanB<<<1, 256, 0, stream>>>(bsum, nb_scan);
        k_scanC<<<(N + 256) / 256, 256, 0, stream>>>(rowptr, cursor, bsum, N, E);
        k_scatter<<<(E + 255) / 256, 256, 0, stream>>>(ei, et, pl, cursor, ep, E);

        for (int layer = 0; layer < 2; ++layer) {
            const float* xin  = layer ? aggr1 : x;
            const float* W    = layer ? W2 : W1;
            const float* bias = layer ? b2 : b1;
            float* dest       = layer ? out : aggr1;
            k_transform<<<dim3(gx, 2), 256, 0, stream>>>(xin, W, Y, N, 0, RR / 2, 0);
            k_aggregate<<<(N + 7) / 8, 256, 0, stream>>>(Y, rowptr, ep, et, pl,
                                                         bias, dest, N, E);
        }
        return;
    }

    // chunked fallback: Yc = ndf bf16, aggr = ndf fp32
    ushort_t* Yc = (ushort_t*)wsb;
    float* ag    = (float*)(wsb + ndf * 2);
    const int gEdgeT = (E + N + 7) / 8;
    const int gQuad  = (N * (DD / 4) + 255) / 256;
    float* hid = ag;  // layer-1 hidden

    for (int layer = 0; layer < 2; ++layer) {
        const float* xin  = layer ? hid : x;
        const float* W    = layer ? W2 : W1;
        const float* bias = layer ? b2 : b1;
        float* aggr       = layer ? out : ag;
        k_zero<<<1024, 256, 0, stream>>>(aggr, ndf);
        for (int r = 0; r < RR; ++r) {
            k_transform<<<dim3(gx, 1), 256, 0, stream>>>(xin, W, Yc, N, r, 1, r);
            k_edges<<<gEdgeT, 256, 0, stream>>>(ei, et, pl, Yc, aggr, N, E, E + N, r);
        }
        k_bias_relu<<<gQuad, 256, 0, stream>>>(aggr, bias, layer ? out : hid, N);
    }
}

// Round 4
// 296.561 us; speedup vs baseline: 2.5640x; 1.5748x over previous
//
#include <hip/hip_runtime.h>

#define DD 64
#define RR 16
#define EPSF 1e-9f

typedef unsigned short ushort_t;
typedef __bf16 bf16x8 __attribute__((ext_vector_type(8)));
typedef float f32x4 __attribute__((ext_vector_type(4)));
union F8 { uint4 u; bf16x8 v; };

__device__ __forceinline__ void fma4(float4& a, const float4& w, float s) {
    a.x = fmaf(w.x, s, a.x); a.y = fmaf(w.y, s, a.y);
    a.z = fmaf(w.z, s, a.z); a.w = fmaf(w.w, s, a.w);
}

__device__ __forceinline__ unsigned f2bf(float f) {
    unsigned u = __float_as_uint(f);
    return (u + 0x7FFFu + ((u >> 16) & 1u)) >> 16;   // RNE
}
__device__ __forceinline__ uint2 pk4(float4 v) {
    return make_uint2(f2bf(v.x) | (f2bf(v.y) << 16),
                      f2bf(v.z) | (f2bf(v.w) << 16));
}
__device__ __forceinline__ float bf_lo(unsigned u) { return __uint_as_float(u << 16); }
__device__ __forceinline__ float bf_hi(unsigned u) { return __uint_as_float(u & 0xFFFF0000u); }

// ---------------- W pre-pack into MFMA B-fragment layout -----------------------
// Wb[r][kb][ot][lane][j] = bf16(W[r][kb*32 + (lane>>4)*8 + j][ot*16 + (lane&15)])
__global__ __launch_bounds__(256) void k_packW(
    const float* __restrict__ W, ushort_t* __restrict__ Wb)
{
    int t = blockIdx.x * 256 + threadIdx.x;
    if (t >= RR * 2 * 4 * 64) return;
    int lane = t & 63;
    int ot = (t >> 6) & 3;
    int kb = (t >> 8) & 1;
    int r  = t >> 9;
    int o  = ot * 16 + (lane & 15);
    int k0 = kb * 32 + (lane >> 4) * 8;
    const float* w = W + ((size_t)r * DD + k0) * DD + o;
    unsigned d[4];
    #pragma unroll
    for (int p = 0; p < 4; ++p)
        d[p] = f2bf(w[(2 * p) * DD]) | (f2bf(w[(2 * p + 1) * DD]) << 16);
    ((uint4*)Wb)[t] = make_uint4(d[0], d[1], d[2], d[3]);
}

// ---------------- MFMA transform: Y[r][n][o] bf16 = x[n][:] @ W[r] -------------
// Wave = 16 nodes; block = 4 waves = 64 nodes; loops all 16 relations.
__global__ __launch_bounds__(256) void k_transform_mfma(
    const float* __restrict__ x, const ushort_t* __restrict__ Wb,
    ushort_t* __restrict__ Y, int N)
{
    const int lane = threadIdx.x & 63;
    const int m0 = (blockIdx.x * 4 + (threadIdx.x >> 6)) * 16;
    if (m0 >= N) return;
    const int quad = lane >> 4, c = lane & 15;

    int node = m0 + c; if (node >= N) node = N - 1;
    const float* xr = x + (size_t)node * DD + quad * 8;
    float4 xa = *(const float4*)xr;
    float4 xb = *(const float4*)(xr + 4);
    float4 xc = *(const float4*)(xr + 32);
    float4 xd = *(const float4*)(xr + 36);
    F8 a0, a1;
    { uint2 p = pk4(xa), q = pk4(xb); a0.u = make_uint4(p.x, p.y, q.x, q.y); }
    { uint2 p = pk4(xc), q = pk4(xd); a1.u = make_uint4(p.x, p.y, q.x, q.y); }

    const uint4* wbp = (const uint4*)Wb + lane;
    const bool full = (m0 + 16 <= N);

    for (int r = 0; r < RR; ++r) {
        ushort_t* yr = Y + ((size_t)r * N + m0) * DD + c;
        #pragma unroll
        for (int ot = 0; ot < 4; ++ot) {
            F8 b0, b1;
            b0.u = wbp[(size_t)(r * 8 + ot) * 64];
            b1.u = wbp[(size_t)(r * 8 + 4 + ot) * 64];
            f32x4 acc = {0.f, 0.f, 0.f, 0.f};
            acc = __builtin_amdgcn_mfma_f32_16x16x32_bf16(a0.v, b0.v, acc, 0, 0, 0);
            acc = __builtin_amdgcn_mfma_f32_16x16x32_bf16(a1.v, b1.v, acc, 0, 0, 0);
            ushort_t* yp = yr + (ot << 4);
            if (full) {
                #pragma unroll
                for (int g = 0; g < 4; ++g)
                    yp[(size_t)(quad * 4 + g) * DD] = (ushort_t)f2bf(acc[g]);
            } else {
                #pragma unroll
                for (int g = 0; g < 4; ++g)
                    if (m0 + quad * 4 + g < N)
                        yp[(size_t)(quad * 4 + g) * DD] = (ushort_t)f2bf(acc[g]);
            }
        }
    }
}

// ---------------- fallback vector-ALU transform (chunked path) -----------------
__global__ __launch_bounds__(256) void k_transform(
    const float* __restrict__ x, const float* __restrict__ W,
    ushort_t* __restrict__ Y, int N, int r_base, int r_cnt, int yr_off)
{
    __shared__ float xt[DD * 128];
    __shared__ float ws[DD * DD];
    const int n0 = blockIdx.x * 128;
    const int tid = threadIdx.x;

    #pragma unroll
    for (int c = 0; c < 8; ++c) {
        int idx = c * 256 + tid;
        int n  = idx >> 4;
        int i4 = (idx & 15) << 2;
        int gn = n0 + n;
        float4 v = make_float4(0.f, 0.f, 0.f, 0.f);
        if (gn < N) v = ((const float4*)(x + (size_t)gn * DD))[idx & 15];
        int n4 = n >> 2, nr = n & 3;
        float vv[4] = {v.x, v.y, v.z, v.w};
        #pragma unroll
        for (int k = 0; k < 4; ++k) {
            int i = i4 + k;
            int swz = (i >> 2) & 7;
            xt[i * 128 + (((n4 ^ swz) << 2) | nr)] = vv[k];
        }
    }

    const int j  = tid & 15;
    const int nq = tid >> 4;

    for (int rr = 0; rr < r_cnt; ++rr) {
        const int r = r_base + blockIdx.y * r_cnt + rr;
        __syncthreads();
        {
            const float4* Wv = (const float4*)(W + (size_t)r * DD * DD);
            float4* wv = (float4*)ws;
            #pragma unroll
            for (int c = 0; c < 4; ++c) wv[c * 256 + tid] = Wv[c * 256 + tid];
        }
        __syncthreads();

        float4 acc[8];
        #pragma unroll
        for (int m = 0; m < 8; ++m) acc[m] = make_float4(0.f, 0.f, 0.f, 0.f);

        #pragma unroll 4
        for (int i = 0; i < DD; ++i) {
            const int swz = (i >> 2) & 7;
            const float4 wv = *(const float4*)&ws[i * DD + 4 * j];
            #pragma unroll
            for (int h = 0; h < 2; ++h) {
                const int col4 = (2 * nq + h) ^ swz;
                const float4 xv = *(const float4*)&xt[i * 128 + (col4 << 2)];
                fma4(acc[4 * h + 0], wv, xv.x);
                fma4(acc[4 * h + 1], wv, xv.y);
                fma4(acc[4 * h + 2], wv, xv.z);
                fma4(acc[4 * h + 3], wv, xv.w);
            }
        }

        const size_t ybase = (size_t)(r - yr_off) * N;
        #pragma unroll
        for (int m = 0; m < 8; ++m) {
            int node = n0 + 8 * nq + 4 * (m >> 2) + (m & 3);
            if (node < N)
                *(uint2*)(Y + (ybase + node) * DD + 4 * j) = pk4(acc[m]);
        }
    }
}

// ---------------- CSR build ----------------------------------------------------

__global__ __launch_bounds__(256) void k_zero_int(int* __restrict__ p, int n)
{
    int i = blockIdx.x * 256 + threadIdx.x;
    if (i < n) p[i] = 0;
}

__global__ __launch_bounds__(256) void k_hist(
    const int* __restrict__ ei, int* __restrict__ deg, int E)
{
    int e = blockIdx.x * 256 + threadIdx.x;
    if (e < E) atomicAdd(&deg[ei[E + e]], 1);
}

__global__ __launch_bounds__(256) void k_scanA(
    const int* __restrict__ deg, int* __restrict__ rowptr,
    int* __restrict__ bsum, int N)
{
    __shared__ int sh[256];
    const int b = blockIdx.x, t = threadIdx.x;
    const int base = b * 1024 + t * 4;
    int v[4], s = 0;
    #pragma unroll
    for (int k = 0; k < 4; ++k) {
        int i = base + k;
        v[k] = (i < N) ? deg[i] : 0;
        s += v[k];
    }
    sh[t] = s;
    __syncthreads();
    for (int off = 1; off < 256; off <<= 1) {
        int tmp = (t >= off) ? sh[t - off] : 0;
        __syncthreads();
        sh[t] += tmp;
        __syncthreads();
    }
    if (t == 255) bsum[b] = sh[255];
    int run = sh[t] - s;
    #pragma unroll
    for (int k = 0; k < 4; ++k) {
        int i = base + k;
        if (i < N) rowptr[i] = run;
        run += v[k];
    }
}

__global__ __launch_bounds__(256) void k_scanB(int* __restrict__ bsum, int nb)
{
    __shared__ int sh[256];
    int t = threadIdx.x;
    int v = (t < nb) ? bsum[t] : 0;
    sh[t] = v;
    __syncthreads();
    for (int off = 1; off < 256; off <<= 1) {
        int tmp = (t >= off) ? sh[t - off] : 0;
        __syncthreads();
        sh[t] += tmp;
        __syncthreads();
    }
    if (t < nb) bsum[t] = sh[t] - v;
}

__global__ __launch_bounds__(256) void k_scanC(
    int* __restrict__ rowptr, int* __restrict__ cursor,
    const int* __restrict__ bsum, int N, int E)
{
    int i = blockIdx.x * 256 + threadIdx.x;
    if (i < N) {
        int v = rowptr[i] + bsum[i >> 10];
        rowptr[i] = v;
        cursor[i] = v;
    }
    if (i == N) rowptr[N] = E;
}

__global__ __launch_bounds__(256) void k_scatter(
    const int* __restrict__ ei, const int* __restrict__ et,
    const float* __restrict__ pl, int* __restrict__ cursor,
    uint2* __restrict__ ep, int E)
{
    int e = blockIdx.x * 256 + threadIdx.x;
    if (e >= E) return;
    int dst = ei[E + e];
    int src = ei[e];
    int rt  = et[e];
    float iv = 1.0f / fmaxf(pl[e], EPSF);
    int pos = atomicAdd(&cursor[dst], 1);
    ep[pos] = make_uint2((unsigned)src | ((unsigned)rt << 20), __float_as_uint(iv));
}

// ---------------- fused aggregate, 4-deep gather pipeline ----------------------

__global__ __launch_bounds__(256) void k_aggregate(
    const ushort_t* __restrict__ Y, const int* __restrict__ rowptr,
    const uint2* __restrict__ ep,
    const int* __restrict__ et, const float* __restrict__ pl,
    const float* __restrict__ bias, float* __restrict__ out, int N, int E)
{
    const int n = blockIdx.x * 8 + (threadIdx.x >> 5);
    const int lane = threadIdx.x & 31;
    if (n >= N) return;

    int rts = et[E + n];
    float ivs = 1.0f / fmaxf(pl[E + n], EPSF);
    unsigned yv = *(const unsigned*)(Y + ((size_t)rts * N + n) * DD + 2 * lane);
    float accx = bf_lo(yv) * ivs;
    float accy = bf_hi(yv) * ivs;

    const int beg = rowptr[n], end = rowptr[n + 1];
    for (int p0 = beg; p0 < end; p0 += 32) {
        int cnt = end - p0; if (cnt > 32) cnt = 32;
        unsigned pk = 0, ivb = 0;
        if (lane < cnt) { uint2 m = ep[p0 + lane]; pk = m.x; ivb = m.y; }
        int jj = 0;
        for (; jj + 4 <= cnt; jj += 4) {
            unsigned v[4]; float ivv[4];
            #pragma unroll
            for (int q = 0; q < 4; ++q) {
                unsigned pkj = (unsigned)__shfl((int)pk, jj + q, 32);
                ivv[q] = __uint_as_float((unsigned)__shfl((int)ivb, jj + q, 32));
                v[q] = *(const unsigned*)(Y + (((size_t)(pkj >> 20)) * N + (pkj & 0xFFFFFu)) * DD + 2 * lane);
            }
            #pragma unroll
            for (int q = 0; q < 4; ++q) {
                accx = fmaf(bf_lo(v[q]), ivv[q], accx);
                accy = fmaf(bf_hi(v[q]), ivv[q], accy);
            }
        }
        for (; jj < cnt; ++jj) {
            unsigned pkj = (unsigned)__shfl((int)pk, jj, 32);
            float ivj = __uint_as_float((unsigned)__shfl((int)ivb, jj, 32));
            unsigned v = *(const unsigned*)(Y + (((size_t)(pkj >> 20)) * N + (pkj & 0xFFFFFu)) * DD + 2 * lane);
            accx = fmaf(bf_lo(v), ivj, accx);
            accy = fmaf(bf_hi(v), ivj, accy);
        }
    }
    float2 bb = *(const float2*)(bias + 2 * lane);
    float2 o;
    o.x = fmaxf(accx + bb.x, 0.f);
    o.y = fmaxf(accy + bb.y, 0.f);
    *(float2*)(out + (size_t)n * DD + 2 * lane) = o;
}

// ---------------- fallback (chunked, atomic) -----------------------------------

__global__ __launch_bounds__(256) void k_edges(
    const int* __restrict__ ei, const int* __restrict__ et,
    const float* __restrict__ pl, const ushort_t* __restrict__ Y,
    float* __restrict__ aggr, int N, int E, int Etot, int rel_filter)
{
    int sub = threadIdx.x >> 5;
    int lane = threadIdx.x & 31;
    int e = blockIdx.x * 8 + sub;
    if (e >= Etot) return;
    int rt = et[e];
    int yrel = rt;
    if (rel_filter >= 0) { if (rt != rel_filter) return; yrel = 0; }
    int src, dst;
    if (e < E) { src = ei[e]; dst = ei[E + e]; }
    else       { src = dst = e - E; }
    float inv = 1.0f / fmaxf(pl[e], EPSF);
    unsigned v = *(const unsigned*)(Y + ((size_t)yrel * N + src) * DD + 2 * lane);
    atomicAdd(&aggr[(size_t)dst * DD + 2 * lane],     bf_lo(v) * inv);
    atomicAdd(&aggr[(size_t)dst * DD + 2 * lane + 1], bf_hi(v) * inv);
}

__global__ __launch_bounds__(256) void k_bias_relu(
    const float* __restrict__ aggr, const float* __restrict__ bias,
    float* __restrict__ out, int N)
{
    int idx = blockIdx.x * 256 + threadIdx.x;
    if (idx >= N * (DD / 4)) return;
    float4 a = ((const float4*)aggr)[idx];
    int o4 = (idx & 15) * 4;
    a.x = fmaxf(a.x + bias[o4 + 0], 0.f);
    a.y = fmaxf(a.y + bias[o4 + 1], 0.f);
    a.z = fmaxf(a.z + bias[o4 + 2], 0.f);
    a.w = fmaxf(a.w + bias[o4 + 3], 0.f);
    ((float4*)out)[idx] = a;
}

__global__ __launch_bounds__(256) void k_zero(float* __restrict__ p, size_t n)
{
    size_t i = (size_t)blockIdx.x * 256 + threadIdx.x;
    size_t stride = (size_t)gridDim.x * 256;
    for (; i < n; i += stride) p[i] = 0.f;
}

extern "C" void kernel_launch(void* const* d_in, const int* in_sizes, int n_in,
                              void* d_out, int out_size, void* d_ws, size_t ws_size,
                              hipStream_t stream)
{
    const float* x  = (const float*)d_in[0];
    const int*   ei = (const int*)d_in[1];
    const int*   et = (const int*)d_in[2];
    const float* pl = (const float*)d_in[3];
    const float* W1 = (const float*)d_in[4];
    const float* b1 = (const float*)d_in[5];
    const float* W2 = (const float*)d_in[6];
    const float* b2 = (const float*)d_in[7];
    float* out = (float*)d_out;

    const int N = in_sizes[0] / DD;
    const int E = in_sizes[1] / 2;
    const size_t ndf = (size_t)N * DD;
    const size_t wb_elems = (size_t)RR * 2 * 4 * 64 * 8;   // 65536 ushorts

    char* wsb = (char*)d_ws;
    ushort_t* Y   = (ushort_t*)wsb;                          // RR*ndf bf16
    float* aggr1  = (float*)(wsb + (size_t)RR * ndf * 2);    // ndf fp32
    ushort_t* Wb1 = (ushort_t*)((char*)aggr1 + ndf * 4);     // 128 KB
    ushort_t* Wb2 = Wb1 + wb_elems;                          // 128 KB
    int* rowptr   = (int*)(Wb2 + wb_elems);                  // N+1
    int* cursor   = rowptr + (N + 1);                        // N
    int* bsum     = cursor + N;                              // 256+1
    uint2* ep     = (uint2*)(bsum + 256 + 1);                // E

    const size_t need_main = (size_t)RR * ndf * 2 + ndf * 4 + wb_elems * 4 +
        ((size_t)(N + 1) + N + 257) * 4 + (size_t)E * 8;
    const int nb_scan = (N + 1023) / 1024;
    const bool main_ok = (ws_size >= need_main) && (nb_scan <= 256);

    if (main_ok) {
        k_packW<<<(RR * 2 * 4 * 64 + 255) / 256, 256, 0, stream>>>(W1, Wb1);
        k_packW<<<(RR * 2 * 4 * 64 + 255) / 256, 256, 0, stream>>>(W2, Wb2);
        k_zero_int<<<(N + 256) / 256, 256, 0, stream>>>(rowptr, N + 1);
        k_hist<<<(E + 255) / 256, 256, 0, stream>>>(ei, rowptr, E);
        k_scanA<<<nb_scan, 256, 0, stream>>>(rowptr, rowptr, bsum, N);
        k_scanB<<<1, 256, 0, stream>>>(bsum, nb_scan);
        k_scanC<<<(N + 256) / 256, 256, 0, stream>>>(rowptr, cursor, bsum, N, E);
        k_scatter<<<(E + 255) / 256, 256, 0, stream>>>(ei, et, pl, cursor, ep, E);

        const int gT = (N + 63) / 64;
        for (int layer = 0; layer < 2; ++layer) {
            const float* xin      = layer ? aggr1 : x;
            const ushort_t* Wb    = layer ? Wb2 : Wb1;
            const float* bias     = layer ? b2 : b1;
            float* dest           = layer ? out : aggr1;
            k_transform_mfma<<<gT, 256, 0, stream>>>(xin, Wb, Y, N);
            k_aggregate<<<(N + 7) / 8, 256, 0, stream>>>(Y, rowptr, ep, et, pl,
                                                         bias, dest, N, E);
        }
        return;
    }

    // chunked fallback: Yc = ndf bf16, aggr = ndf fp32
    ushort_t* Yc = (ushort_t*)wsb;
    float* ag    = (float*)(wsb + ndf * 2);
    const int gx     = (N + 127) / 128;
    const int gEdgeT = (E + N + 7) / 8;
    const int gQuad  = (N * (DD / 4) + 255) / 256;
    float* hid = ag;

    for (int layer = 0; layer < 2; ++layer) {
        const float* xin  = layer ? hid : x;
        const float* W    = layer ? W2 : W1;
        const float* bias = layer ? b2 : b1;
        float* aggr       = layer ? out : ag;
        k_zero<<<1024, 256, 0, stream>>>(aggr, ndf);
        for (int r = 0; r < RR; ++r) {
            k_transform<<<dim3(gx, 1), 256, 0, stream>>>(xin, W, Yc, N, r, 1, r);
            k_edges<<<gEdgeT, 256, 0, stream>>>(ei, et, pl, Yc, aggr, N, E, E + N, r);
        }
        k_bias_relu<<<gQuad, 256, 0, stream>>>(aggr, bias, layer ? out : hid, N);
    }
}